// Round 7
// baseline (21943.810 us; speedup 1.0000x reference)
//
#include <hip/hip_runtime.h>

typedef unsigned int u32;
typedef unsigned short u16;
typedef __attribute__((ext_vector_type(2))) _Float16 h2v;
typedef __attribute__((ext_vector_type(4))) _Float16 f16x4;
typedef __attribute__((ext_vector_type(4))) float f32x4;

#define BB 32
#define TT 2048
#define CC 256
#define ESZ 256
#define GG 1024   // 4*es

// W2 per gate-column = 128 h2-rows (256 k values). Per-thread (4 columns):
//   h2-rows  0..43  -> arch VGPRs  (44 u32 x 4 cols = 176)          [MRV]
//   h2-rows 44..91  -> AGPRs       (48 u32 x 4 cols = 192, "+a" pin) [MRA]
//   h2-rows 92..127 -> LDS         (9 uint4 chunks, 147456 B)        [NLDS]
#define MRV 44
#define MRA 48
#define NLDS 9

// ---------------- helpers ----------------
__device__ __forceinline__ float fdot2u(u32 a, u32 b, float c) {
#if __has_builtin(__builtin_amdgcn_fdot2)
  return __builtin_amdgcn_fdot2(__builtin_bit_cast(h2v, a), __builtin_bit_cast(h2v, b), c, false);
#else
  h2v av = __builtin_bit_cast(h2v, a), bv = __builtin_bit_cast(h2v, b);
  return c + (float)av[0] * (float)bv[0] + (float)av[1] * (float)bv[1];
#endif
}

__device__ __forceinline__ float sigm_f(float x) {
  float e = __builtin_amdgcn_exp2f(x * -1.442695041f);
  return __builtin_amdgcn_rcpf(1.0f + e);
}
__device__ __forceinline__ float tanh_f(float x) {
  float e = __builtin_amdgcn_exp2f(x * 2.885390082f);  // exp(2x)
  return 1.0f - 2.0f * __builtin_amdgcn_rcpf(e + 1.0f);
}

// ---------------- kernel 0: pack W2 (f32 [256][1024] -> h2 rows [128][1024]) ----------------
__global__ void k_pack_w2(const float* __restrict__ W2, u32* __restrict__ W2p) {
  int gid = blockIdx.x * 256 + threadIdx.x;   // m = gid>>10, j = gid&1023
  int m = gid >> 10, j = gid & 1023;
  _Float16 lo = (_Float16)W2[(size_t)(2 * m) * GG + j];
  _Float16 hi = (_Float16)W2[(size_t)(2 * m + 1) * GG + j];
  W2p[gid] = (u32)__builtin_bit_cast(u16, lo) | ((u32)__builtin_bit_cast(u16, hi) << 16);
}

// ---------------- kernel 1: pre = x@W1 + b1 + b2  (f16 MFMA, out f16 [B*T][1024]) ----------------
__global__ __launch_bounds__(256, 2) void k_pre_gemm(
    const float* __restrict__ x, const float* __restrict__ W1,
    const float* __restrict__ b1, const float* __restrict__ b2,
    _Float16* __restrict__ pre) {
  __shared__ __attribute__((aligned(16))) _Float16 Al[128 * 36];
  __shared__ __attribute__((aligned(16))) _Float16 Bl[64 * 36];
  const int tid = threadIdx.x;
  const int lane = tid & 63, wv = tid >> 6;
  const int wr = wv >> 1, wc = wv & 1;
  const int rowBase = blockIdx.x * 128;
  const int colBase = blockIdx.y * 64;

  f32x4 acc[4][2];
#pragma unroll
  for (int mi = 0; mi < 4; ++mi)
#pragma unroll
    for (int ni = 0; ni < 2; ++ni) acc[mi][ni] = (f32x4){0.f, 0.f, 0.f, 0.f};

  for (int k0 = 0; k0 < 256; k0 += 32) {
#pragma unroll
    for (int i = 0; i < 4; ++i) {
      int fidx = tid + 256 * i;
      int row = fidx >> 3, kc = (fidx & 7) * 4;
      const float4 v = *(const float4*)(x + (size_t)(rowBase + row) * 256 + k0 + kc);
      f16x4 hv = { (_Float16)v.x, (_Float16)v.y, (_Float16)v.z, (_Float16)v.w };
      *(f16x4*)&Al[row * 36 + kc] = hv;
    }
#pragma unroll
    for (int i = 0; i < 8; ++i) {
      int idx = tid + 256 * i;
      int k = idx >> 6, n = idx & 63;
      Bl[n * 36 + k] = (_Float16)W1[(size_t)(k0 + k) * GG + colBase + n];
    }
    __syncthreads();

#pragma unroll
    for (int kk = 0; kk < 2; ++kk) {
      int ka = (lane >> 4) * 4 + kk * 16;
      f16x4 af[4], bf[2];
#pragma unroll
      for (int mi = 0; mi < 4; ++mi)
        af[mi] = *(const f16x4*)&Al[(wr * 64 + mi * 16 + (lane & 15)) * 36 + ka];
#pragma unroll
      for (int ni = 0; ni < 2; ++ni)
        bf[ni] = *(const f16x4*)&Bl[(wc * 32 + ni * 16 + (lane & 15)) * 36 + ka];
#pragma unroll
      for (int mi = 0; mi < 4; ++mi)
#pragma unroll
        for (int ni = 0; ni < 2; ++ni)
          acc[mi][ni] = __builtin_amdgcn_mfma_f32_16x16x16f16(af[mi], bf[ni], acc[mi][ni], 0, 0, 0);
    }
    __syncthreads();
  }

#pragma unroll
  for (int ni = 0; ni < 2; ++ni) {
    int col = colBase + wc * 32 + ni * 16 + (lane & 15);
    float bias = b1[col] + b2[col];
#pragma unroll
    for (int mi = 0; mi < 4; ++mi) {
      int r0 = rowBase + wr * 64 + mi * 16 + (lane >> 4) * 4;
#pragma unroll
      for (int rr = 0; rr < 4; ++rr)
        pre[(size_t)(r0 + rr) * GG + col] = (_Float16)(acc[mi][ni][rr] + bias);
    }
  }
}

// ---------------- kernel 2: the recurrence ----------------
// 32 blocks (one per batch), 256 threads (4 waves, 1 wave/SIMD, FULL unified file).
// Thread t owns ALL FOUR gate columns of es-index t: {t, t+256, t+512, t+768}
// -> gates combine in-register, no exchange, 1 barrier/step (h double-buffered).
// W2 storage: 176 arch VGPRs + 192 AGPRs (forced via "+a") + 147KB LDS. Zero
// per-step L2 traffic by construction.
__global__ __launch_bounds__(256, 1)
__attribute__((amdgpu_waves_per_eu(1, 1)))
void k_lstm_rec(
    const _Float16* __restrict__ pre, const u32* __restrict__ W2p,
    const float* __restrict__ h0, const float* __restrict__ c0,
    float* __restrict__ out1, float* __restrict__ out2,
    float* __restrict__ hN, float* __restrict__ cN) {
  extern __shared__ __attribute__((aligned(16))) char smem[];
  uint4* W2Lw = (uint4*)smem;                               // NLDS*1024 uint4 = 147456 B
  const uint4* W2L = (const uint4*)smem;
  _Float16* hbuf = (_Float16*)(smem + NLDS * 1024 * 16);    // [2][256] f16 = 1024 B

  const int t = threadIdx.x;   // es index 0..255
  const int b = blockIdx.x;

  // ---- load W2 columns: col_g = t + 256*g, g=0..3 (f,i,o,ch) ----
  u32 wv0[MRV], wv1[MRV], wv2[MRV], wv3[MRV];   // h2-rows 0..43
#pragma unroll
  for (int m = 0; m < MRV; ++m) {
    wv0[m] = W2p[m * GG + t];
    wv1[m] = W2p[m * GG + t + 256];
    wv2[m] = W2p[m * GG + t + 512];
    wv3[m] = W2p[m * GG + t + 768];
  }
  u32 wa0[MRA], wa1[MRA], wa2[MRA], wa3[MRA];   // h2-rows 44..91 -> AGPRs
#pragma unroll
  for (int m = 0; m < MRA; ++m) {
    wa0[m] = W2p[(MRV + m) * GG + t];
    wa1[m] = W2p[(MRV + m) * GG + t + 256];
    wa2[m] = W2p[(MRV + m) * GG + t + 512];
    wa3[m] = W2p[(MRV + m) * GG + t + 768];
  }
  // LDS-resident h2-rows 92..127: chunk c holds rows 92+4c..92+4c+3, uint4 per col
#pragma unroll
  for (int c = 0; c < NLDS; ++c) {
    int m0 = MRV + MRA + 4 * c;
#pragma unroll
    for (int g = 0; g < 4; ++g) {
      uint4 v;
      v.x = W2p[(m0 + 0) * GG + t + 256 * g];
      v.y = W2p[(m0 + 1) * GG + t + 256 * g];
      v.z = W2p[(m0 + 2) * GG + t + 256 * g];
      v.w = W2p[(m0 + 3) * GG + t + 256 * g];
      W2Lw[c * 1024 + t + 256 * g] = v;
    }
  }

  float creg = c0[b * ESZ + t];
  hbuf[t] = (_Float16)h0[b * ESZ + t];
  float hlast = 0.f;
  __syncthreads();

  const _Float16* preB = pre + (size_t)b * TT * GG;
  _Float16 q0 = preB[t], q1 = preB[t + 256], q2 = preB[t + 512], q3 = preB[t + 768];

  for (int s = 0; s < TT; ++s) {
    // pin storage residency each iteration (empty asm: liveness only)
#pragma unroll
    for (int m = 0; m < MRV; ++m)
      asm volatile("" : "+v"(wv0[m]), "+v"(wv1[m]), "+v"(wv2[m]), "+v"(wv3[m]));
#pragma unroll
    for (int m = 0; m < MRA; ++m)
      asm volatile("" : "+a"(wa0[m]), "+a"(wa1[m]), "+a"(wa2[m]), "+a"(wa3[m]));

    const uint4* hb4 = (const uint4*)(hbuf + (s & 1) * 256);
    float A0 = (float)q0, A1 = (float)q1, A2 = (float)q2, A3 = (float)q3;

    if (s + 1 < TT) {  // prefetch next step's pre (stays in flight across barrier)
      const _Float16* pn = preB + (size_t)(s + 1) * GG;
      q0 = pn[t]; q1 = pn[t + 256]; q2 = pn[t + 512]; q3 = pn[t + 768];
    }

    // group g covers h2-rows 4g..4g+3 (h elements 8g..8g+7), broadcast read
#pragma unroll
    for (int g = 0; g < 32; ++g) {
      uint4 hh = hb4[g];                       // same addr across wave -> broadcast
      u32 hx[4] = {hh.x, hh.y, hh.z, hh.w};
      if (g < MRV / 4) {
#pragma unroll
        for (int r = 0; r < 4; ++r) {
          int m = 4 * g + r;
          A0 = fdot2u(hx[r], wv0[m], A0);
          A1 = fdot2u(hx[r], wv1[m], A1);
          A2 = fdot2u(hx[r], wv2[m], A2);
          A3 = fdot2u(hx[r], wv3[m], A3);
        }
      } else if (g < (MRV + MRA) / 4) {
#pragma unroll
        for (int r = 0; r < 4; ++r) {
          int m = 4 * (g - MRV / 4) + r;
          A0 = fdot2u(hx[r], wa0[m], A0);
          A1 = fdot2u(hx[r], wa1[m], A1);
          A2 = fdot2u(hx[r], wa2[m], A2);
          A3 = fdot2u(hx[r], wa3[m], A3);
        }
      } else {
        const int c = g - (MRV + MRA) / 4;
        uint4 l0 = W2L[c * 1024 + t];
        uint4 l1 = W2L[c * 1024 + t + 256];
        uint4 l2 = W2L[c * 1024 + t + 512];
        uint4 l3 = W2L[c * 1024 + t + 768];
        u32 l0x[4] = {l0.x, l0.y, l0.z, l0.w};
        u32 l1x[4] = {l1.x, l1.y, l1.z, l1.w};
        u32 l2x[4] = {l2.x, l2.y, l2.z, l2.w};
        u32 l3x[4] = {l3.x, l3.y, l3.z, l3.w};
#pragma unroll
        for (int r = 0; r < 4; ++r) {
          A0 = fdot2u(hx[r], l0x[r], A0);
          A1 = fdot2u(hx[r], l1x[r], A1);
          A2 = fdot2u(hx[r], l2x[r], A2);
          A3 = fdot2u(hx[r], l3x[r], A3);
        }
      }
    }

    // gates all local: f=A0, i=A1, o=A2, ch=A3
    float fg = sigm_f(A0);
    float ig = sigm_f(A1);
    float og = sigm_f(A2);
    float ch = tanh_f(A3);
    creg = fg * creg + ig * ch;
    float hv = og * tanh_f(creg);
    hlast = hv;

    out1[(size_t)b * TT * ESZ + (size_t)s * ESZ + t] = hv;   // [B, T*es]
    out2[(size_t)s * (BB * ESZ) + b * ESZ + t] = hv;         // [T, B, es]
    hbuf[((s & 1) ^ 1) * 256 + t] = (_Float16)hv;            // next step's h

    // one barrier per step; LDS-only drain (global ops stay in flight)
    asm volatile("s_waitcnt lgkmcnt(0)" ::: "memory");
    __builtin_amdgcn_s_barrier();
  }

  hN[b * ESZ + t] = hlast;
  cN[b * ESZ + t] = creg;
}

// ---------------- launch ----------------
extern "C" void kernel_launch(void* const* d_in, const int* in_sizes, int n_in,
                              void* d_out, int out_size, void* d_ws, size_t ws_size,
                              hipStream_t stream) {
  const float* x  = (const float*)d_in[0];
  const float* h0 = (const float*)d_in[1];
  const float* c0 = (const float*)d_in[2];
  const float* W1 = (const float*)d_in[3];
  const float* W2 = (const float*)d_in[4];
  const float* b1 = (const float*)d_in[5];
  const float* b2 = (const float*)d_in[6];

  float* out1 = (float*)d_out;
  float* out2 = out1 + (size_t)BB * TT * ESZ;
  float* hN   = out2 + (size_t)BB * TT * ESZ;
  float* cN   = hN + BB * ESZ;

  _Float16* pre = (_Float16*)d_ws;                                  // 128 MB
  u32* W2p = (u32*)((char*)d_ws + (size_t)BB * TT * GG * 2);        // 512 KB

  k_pack_w2<<<512, 256, 0, stream>>>(W2, W2p);
  k_pre_gemm<<<dim3(512, 16), 256, 0, stream>>>(x, W1, b1, b2, pre);

  const int ldsBytes = NLDS * 1024 * 16 + 1024;  // 147456 W2 + 2x256 f16 h buffers
  hipFuncSetAttribute((const void*)k_lstm_rec, hipFuncAttributeMaxDynamicSharedMemorySize, ldsBytes);
  k_lstm_rec<<<BB, 256, ldsBytes, stream>>>(pre, W2p, h0, c0, out1, out2, hN, cN);
}

// Round 8
// 4822.345 us; speedup vs baseline: 4.5504x; 4.5504x over previous
//
#include <hip/hip_runtime.h>

typedef unsigned int u32;
typedef unsigned short u16;
typedef __attribute__((ext_vector_type(2))) _Float16 h2v;
typedef __attribute__((ext_vector_type(4))) _Float16 f16x4;
typedef __attribute__((ext_vector_type(4))) float f32x4;

#define BB 32
#define TT 2048
#define CC 256
#define ESZ 256
#define GG 1024   // 4*es

// W2 per gate-column = 128 h2-rows (256 k values). Per-thread (4 columns):
//   h2-rows   0..47  -> arch VGPRs (48 x 4 = 192 regs)                 [MRV]
//   h2-rows  48..111 -> AGPRs (64 x 4 = 256, explicit accvgpr asm)     [MRA]
//   h2-rows 112..127 -> LDS (4 uint4 chunks x 1024 cols = 65536 B)     [NLC]
#define MRV 48
#define MRA 64
#define NLC 4

// ---------------- helpers ----------------
__device__ __forceinline__ float fdot2u(u32 a, u32 b, float c) {
#if __has_builtin(__builtin_amdgcn_fdot2)
  return __builtin_amdgcn_fdot2(__builtin_bit_cast(h2v, a), __builtin_bit_cast(h2v, b), c, false);
#else
  h2v av = __builtin_bit_cast(h2v, a), bv = __builtin_bit_cast(h2v, b);
  return c + (float)av[0] * (float)bv[0] + (float)av[1] * (float)bv[1];
#endif
}

__device__ __forceinline__ float sigm_f(float x) {
  float e = __builtin_amdgcn_exp2f(x * -1.442695041f);
  return __builtin_amdgcn_rcpf(1.0f + e);
}
__device__ __forceinline__ float tanh_f(float x) {
  float e = __builtin_amdgcn_exp2f(x * 2.885390082f);  // exp(2x)
  return 1.0f - 2.0f * __builtin_amdgcn_rcpf(e + 1.0f);
}

// ---------------- kernel 0: pack W2 (f32 [256][1024] -> h2 rows [128][1024]) ----------------
__global__ void k_pack_w2(const float* __restrict__ W2, u32* __restrict__ W2p) {
  int gid = blockIdx.x * 256 + threadIdx.x;   // m = gid>>10, j = gid&1023
  int m = gid >> 10, j = gid & 1023;
  _Float16 lo = (_Float16)W2[(size_t)(2 * m) * GG + j];
  _Float16 hi = (_Float16)W2[(size_t)(2 * m + 1) * GG + j];
  W2p[gid] = (u32)__builtin_bit_cast(u16, lo) | ((u32)__builtin_bit_cast(u16, hi) << 16);
}

// ---------------- kernel 1: pre = x@W1 + b1 + b2  (f16 MFMA, out f16 [B*T][1024]) ----------------
__global__ __launch_bounds__(256, 2) void k_pre_gemm(
    const float* __restrict__ x, const float* __restrict__ W1,
    const float* __restrict__ b1, const float* __restrict__ b2,
    _Float16* __restrict__ pre) {
  __shared__ __attribute__((aligned(16))) _Float16 Al[128 * 36];
  __shared__ __attribute__((aligned(16))) _Float16 Bl[64 * 36];
  const int tid = threadIdx.x;
  const int lane = tid & 63, wv = tid >> 6;
  const int wr = wv >> 1, wc = wv & 1;
  const int rowBase = blockIdx.x * 128;
  const int colBase = blockIdx.y * 64;

  f32x4 acc[4][2];
#pragma unroll
  for (int mi = 0; mi < 4; ++mi)
#pragma unroll
    for (int ni = 0; ni < 2; ++ni) acc[mi][ni] = (f32x4){0.f, 0.f, 0.f, 0.f};

  for (int k0 = 0; k0 < 256; k0 += 32) {
#pragma unroll
    for (int i = 0; i < 4; ++i) {
      int fidx = tid + 256 * i;
      int row = fidx >> 3, kc = (fidx & 7) * 4;
      const float4 v = *(const float4*)(x + (size_t)(rowBase + row) * 256 + k0 + kc);
      f16x4 hv = { (_Float16)v.x, (_Float16)v.y, (_Float16)v.z, (_Float16)v.w };
      *(f16x4*)&Al[row * 36 + kc] = hv;
    }
#pragma unroll
    for (int i = 0; i < 8; ++i) {
      int idx = tid + 256 * i;
      int k = idx >> 6, n = idx & 63;
      Bl[n * 36 + k] = (_Float16)W1[(size_t)(k0 + k) * GG + colBase + n];
    }
    __syncthreads();

#pragma unroll
    for (int kk = 0; kk < 2; ++kk) {
      int ka = (lane >> 4) * 4 + kk * 16;
      f16x4 af[4], bf[2];
#pragma unroll
      for (int mi = 0; mi < 4; ++mi)
        af[mi] = *(const f16x4*)&Al[(wr * 64 + mi * 16 + (lane & 15)) * 36 + ka];
#pragma unroll
      for (int ni = 0; ni < 2; ++ni)
        bf[ni] = *(const f16x4*)&Bl[(wc * 32 + ni * 16 + (lane & 15)) * 36 + ka];
#pragma unroll
      for (int mi = 0; mi < 4; ++mi)
#pragma unroll
        for (int ni = 0; ni < 2; ++ni)
          acc[mi][ni] = __builtin_amdgcn_mfma_f32_16x16x16f16(af[mi], bf[ni], acc[mi][ni], 0, 0, 0);
    }
    __syncthreads();
  }

#pragma unroll
  for (int ni = 0; ni < 2; ++ni) {
    int col = colBase + wc * 32 + ni * 16 + (lane & 15);
    float bias = b1[col] + b2[col];
#pragma unroll
    for (int mi = 0; mi < 4; ++mi) {
      int r0 = rowBase + wr * 64 + mi * 16 + (lane >> 4) * 4;
#pragma unroll
      for (int rr = 0; rr < 4; ++rr)
        pre[(size_t)(r0 + rr) * GG + col] = (_Float16)(acc[mi][ni][rr] + bias);
    }
  }
}

// ---------------- kernel 2: the recurrence ----------------
// 32 blocks, 256 threads (4 waves, 1/SIMD -> 256 arch + 256 acc unified regs).
// Thread t owns all 4 gate columns of es-index t -> gates combine in-register,
// 1 barrier/step, h double-buffered in LDS. W2 fully resident:
// 192 arch VGPRs + 256 AGPRs (explicit v_accvgpr_write/read) + 65 KB LDS.
// h distributed via v_readlane only (VALU pipe; no DS-latency exposure).
__global__ __launch_bounds__(256, 1)
__attribute__((amdgpu_waves_per_eu(1, 1)))
void k_lstm_rec(
    const _Float16* __restrict__ pre, const u32* __restrict__ W2p,
    const float* __restrict__ h0, const float* __restrict__ c0,
    float* __restrict__ out1, float* __restrict__ out2,
    float* __restrict__ hN, float* __restrict__ cN) {
  extern __shared__ __attribute__((aligned(16))) char smem[];
  uint4* W2Lw = (uint4*)smem;                               // NLC*1024 uint4 = 65536 B
  const uint4* W2L = (const uint4*)smem;
  _Float16* hbuf = (_Float16*)(smem + NLC * 1024 * 16);     // [2][256] f16 = 1024 B

  const int t = threadIdx.x;   // es index 0..255
  const int b = blockIdx.x;
  const int lane = t & 63;

  // ---- arch-VGPR weights: h2-rows 0..MRV-1, cols {t, t+256, t+512, t+768} ----
  u32 wv0[MRV], wv1[MRV], wv2[MRV], wv3[MRV];
#pragma unroll
  for (int m = 0; m < MRV; ++m) {
    wv0[m] = W2p[m * GG + t];
    wv1[m] = W2p[m * GG + t + 256];
    wv2[m] = W2p[m * GG + t + 512];
    wv3[m] = W2p[m * GG + t + 768];
  }
#pragma unroll
  for (int m = 0; m < MRV; ++m)
    asm volatile("" : "+v"(wv0[m]), "+v"(wv1[m]), "+v"(wv2[m]), "+v"(wv3[m]));  // pin ONCE

  // ---- AGPR weights: h2-rows MRV..MRV+MRA-1, explicit accvgpr_write ----
  u32 wa0[MRA], wa1[MRA], wa2[MRA], wa3[MRA];
#pragma unroll
  for (int m = 0; m < MRA; ++m) {
    u32 t0 = W2p[(MRV + m) * GG + t];
    u32 t1 = W2p[(MRV + m) * GG + t + 256];
    u32 t2 = W2p[(MRV + m) * GG + t + 512];
    u32 t3 = W2p[(MRV + m) * GG + t + 768];
    asm("v_accvgpr_write_b32 %0, %1" : "=a"(wa0[m]) : "v"(t0));
    asm("v_accvgpr_write_b32 %0, %1" : "=a"(wa1[m]) : "v"(t1));
    asm("v_accvgpr_write_b32 %0, %1" : "=a"(wa2[m]) : "v"(t2));
    asm("v_accvgpr_write_b32 %0, %1" : "=a"(wa3[m]) : "v"(t3));
  }

  // ---- LDS weights: h2-rows MRV+MRA..127, chunk c = rows MRV+MRA+4c..+3 ----
#pragma unroll
  for (int c = 0; c < NLC; ++c) {
    int m0 = MRV + MRA + 4 * c;
#pragma unroll
    for (int g = 0; g < 4; ++g) {
      uint4 v;
      v.x = W2p[(m0 + 0) * GG + t + 256 * g];
      v.y = W2p[(m0 + 1) * GG + t + 256 * g];
      v.z = W2p[(m0 + 2) * GG + t + 256 * g];
      v.w = W2p[(m0 + 3) * GG + t + 256 * g];
      W2Lw[c * 1024 + t + 256 * g] = v;
    }
  }

  float creg = c0[b * ESZ + t];
  hbuf[t] = (_Float16)h0[b * ESZ + t];
  float hlast = 0.f;
  __syncthreads();

  const _Float16* preB = pre + (size_t)b * TT * GG;
  _Float16 q0 = preB[t], q1 = preB[t + 256], q2 = preB[t + 512], q3 = preB[t + 768];

  for (int s = 0; s < TT; ++s) {
    const u32* hrow = (const u32*)(hbuf + (s & 1) * 256);  // h as 128 h2
    u32 hv0 = hrow[lane];        // h2-rows 0..63 spread over lanes
    u32 hv1 = hrow[64 + lane];   // h2-rows 64..127

    float A0 = (float)q0, A1 = (float)q1, A2 = (float)q2, A3 = (float)q3;
    if (s + 1 < TT) {  // prefetch next step's pre (stays in flight across barrier)
      const _Float16* pn = preB + (size_t)(s + 1) * GG;
      q0 = pn[t]; q1 = pn[t + 256]; q2 = pn[t + 512]; q3 = pn[t + 768];
    }

    // part A: arch-VGPR rows 0..MRV-1 (readlane from hv0)
#pragma unroll
    for (int m = 0; m < MRV; ++m) {
      u32 hm = (u32)__builtin_amdgcn_readlane((int)hv0, m);
      A0 = fdot2u(hm, wv0[m], A0);
      A1 = fdot2u(hm, wv1[m], A1);
      A2 = fdot2u(hm, wv2[m], A2);
      A3 = fdot2u(hm, wv3[m], A3);
    }
    // part B: AGPR rows MRV..MRV+MRA-1 (accvgpr_read at use; "a" pins residency)
#pragma unroll
    for (int i = 0; i < MRA; ++i) {
      const int row = MRV + i;  // 48..111
      u32 hm = (row < 64) ? (u32)__builtin_amdgcn_readlane((int)hv0, row)
                          : (u32)__builtin_amdgcn_readlane((int)hv1, row - 64);
      u32 t0, t1, t2, t3;
      asm("v_accvgpr_read_b32 %0, %1" : "=v"(t0) : "a"(wa0[i]));
      asm("v_accvgpr_read_b32 %0, %1" : "=v"(t1) : "a"(wa1[i]));
      asm("v_accvgpr_read_b32 %0, %1" : "=v"(t2) : "a"(wa2[i]));
      asm("v_accvgpr_read_b32 %0, %1" : "=v"(t3) : "a"(wa3[i]));
      A0 = fdot2u(hm, t0, A0);
      A1 = fdot2u(hm, t1, A1);
      A2 = fdot2u(hm, t2, A2);
      A3 = fdot2u(hm, t3, A3);
    }
    // part C: LDS rows 112..127 (weights per-lane b128, h via readlane from hv1)
#pragma unroll
    for (int c = 0; c < NLC; ++c) {
      uint4 l0 = W2L[c * 1024 + t];
      uint4 l1 = W2L[c * 1024 + t + 256];
      uint4 l2 = W2L[c * 1024 + t + 512];
      uint4 l3 = W2L[c * 1024 + t + 768];
      u32 l0x[4] = {l0.x, l0.y, l0.z, l0.w};
      u32 l1x[4] = {l1.x, l1.y, l1.z, l1.w};
      u32 l2x[4] = {l2.x, l2.y, l2.z, l2.w};
      u32 l3x[4] = {l3.x, l3.y, l3.z, l3.w};
#pragma unroll
      for (int r = 0; r < 4; ++r) {
        u32 hm = (u32)__builtin_amdgcn_readlane((int)hv1, (MRV + MRA - 64) + 4 * c + r);
        A0 = fdot2u(hm, l0x[r], A0);
        A1 = fdot2u(hm, l1x[r], A1);
        A2 = fdot2u(hm, l2x[r], A2);
        A3 = fdot2u(hm, l3x[r], A3);
      }
    }

    // gates all thread-local: f=A0, i=A1, o=A2, ch=A3
    float fg = sigm_f(A0);
    float ig = sigm_f(A1);
    float og = sigm_f(A2);
    float ch = tanh_f(A3);
    creg = fg * creg + ig * ch;
    float hv = og * tanh_f(creg);
    hlast = hv;

    out1[(size_t)b * TT * ESZ + (size_t)s * ESZ + t] = hv;   // [B, T*es]
    out2[(size_t)s * (BB * ESZ) + b * ESZ + t] = hv;         // [T, B, es]
    hbuf[((s & 1) ^ 1) * 256 + t] = (_Float16)hv;            // next step's h

    // one barrier/step; LDS-only drain (global loads/stores stay in flight)
    asm volatile("s_waitcnt lgkmcnt(0)" ::: "memory");
    __builtin_amdgcn_s_barrier();
  }

  hN[b * ESZ + t] = hlast;
  cN[b * ESZ + t] = creg;
}

// ---------------- launch ----------------
extern "C" void kernel_launch(void* const* d_in, const int* in_sizes, int n_in,
                              void* d_out, int out_size, void* d_ws, size_t ws_size,
                              hipStream_t stream) {
  const float* x  = (const float*)d_in[0];
  const float* h0 = (const float*)d_in[1];
  const float* c0 = (const float*)d_in[2];
  const float* W1 = (const float*)d_in[3];
  const float* W2 = (const float*)d_in[4];
  const float* b1 = (const float*)d_in[5];
  const float* b2 = (const float*)d_in[6];

  float* out1 = (float*)d_out;
  float* out2 = out1 + (size_t)BB * TT * ESZ;
  float* hN   = out2 + (size_t)BB * TT * ESZ;
  float* cN   = hN + BB * ESZ;

  _Float16* pre = (_Float16*)d_ws;                                  // 128 MB
  u32* W2p = (u32*)((char*)d_ws + (size_t)BB * TT * GG * 2);        // 512 KB

  k_pack_w2<<<512, 256, 0, stream>>>(W2, W2p);
  k_pre_gemm<<<dim3(512, 16), 256, 0, stream>>>(x, W1, b1, b2, pre);

  const int ldsBytes = NLC * 1024 * 16 + 1024;  // 65536 W2 + 2x256 f16 h buffers
  hipFuncSetAttribute((const void*)k_lstm_rec, hipFuncAttributeMaxDynamicSharedMemorySize, ldsBytes);
  k_lstm_rec<<<BB, 256, ldsBytes, stream>>>(pre, W2p, h0, c0, out1, out2, hN, cN);
}

// Round 9
// 3910.667 us; speedup vs baseline: 5.6113x; 1.2331x over previous
//
#include <hip/hip_runtime.h>

typedef unsigned int u32;
typedef unsigned short u16;
typedef __attribute__((ext_vector_type(2))) _Float16 h2v;
typedef __attribute__((ext_vector_type(4))) _Float16 f16x4;
typedef __attribute__((ext_vector_type(4))) float f32x4;

#define BB 32
#define TT 2048
#define CC 256
#define ESZ 256
#define GG 1024   // 4*es

// W2 per gate-column = 128 h2-rows. Per-thread (4 columns):
//   h2-rows   0..47  -> arch VGPRs (48 x 4 = 192 regs)                 [MRV]
//   h2-rows  48..111 -> AGPRs (64 x 4 = 256, explicit accvgpr asm)     [MRA]
//   h2-rows 112..127 -> LDS (4 uint4 chunks x 1024 cols = 65536 B)     [NLC]
#define MRV 48
#define MRA 64
#define NLC 4

// ---------------- helpers ----------------
__device__ __forceinline__ float fdot2u(u32 a, u32 b, float c) {
#if __has_builtin(__builtin_amdgcn_fdot2)
  return __builtin_amdgcn_fdot2(__builtin_bit_cast(h2v, a), __builtin_bit_cast(h2v, b), c, false);
#else
  h2v av = __builtin_bit_cast(h2v, a), bv = __builtin_bit_cast(h2v, b);
  return c + (float)av[0] * (float)bv[0] + (float)av[1] * (float)bv[1];
#endif
}

__device__ __forceinline__ float sigm_f(float x) {
  float e = __builtin_amdgcn_exp2f(x * -1.442695041f);
  return __builtin_amdgcn_rcpf(1.0f + e);
}
__device__ __forceinline__ float tanh_f(float x) {
  float e = __builtin_amdgcn_exp2f(x * 2.885390082f);  // exp(2x)
  return 1.0f - 2.0f * __builtin_amdgcn_rcpf(e + 1.0f);
}

// ---------------- kernel 0: pack W2 (f32 [256][1024] -> h2 rows [128][1024]) ----------------
__global__ void k_pack_w2(const float* __restrict__ W2, u32* __restrict__ W2p) {
  int gid = blockIdx.x * 256 + threadIdx.x;   // m = gid>>10, j = gid&1023
  int m = gid >> 10, j = gid & 1023;
  _Float16 lo = (_Float16)W2[(size_t)(2 * m) * GG + j];
  _Float16 hi = (_Float16)W2[(size_t)(2 * m + 1) * GG + j];
  W2p[gid] = (u32)__builtin_bit_cast(u16, lo) | ((u32)__builtin_bit_cast(u16, hi) << 16);
}

// ---------------- kernel 1: pre = x@W1 + b1 + b2  (f16 MFMA, out f16 [B*T][1024]) ----------------
__global__ __launch_bounds__(256, 2) void k_pre_gemm(
    const float* __restrict__ x, const float* __restrict__ W1,
    const float* __restrict__ b1, const float* __restrict__ b2,
    _Float16* __restrict__ pre) {
  __shared__ __attribute__((aligned(16))) _Float16 Al[128 * 36];
  __shared__ __attribute__((aligned(16))) _Float16 Bl[64 * 36];
  const int tid = threadIdx.x;
  const int lane = tid & 63, wv = tid >> 6;
  const int wr = wv >> 1, wc = wv & 1;
  const int rowBase = blockIdx.x * 128;
  const int colBase = blockIdx.y * 64;

  f32x4 acc[4][2];
#pragma unroll
  for (int mi = 0; mi < 4; ++mi)
#pragma unroll
    for (int ni = 0; ni < 2; ++ni) acc[mi][ni] = (f32x4){0.f, 0.f, 0.f, 0.f};

  for (int k0 = 0; k0 < 256; k0 += 32) {
#pragma unroll
    for (int i = 0; i < 4; ++i) {
      int fidx = tid + 256 * i;
      int row = fidx >> 3, kc = (fidx & 7) * 4;
      const float4 v = *(const float4*)(x + (size_t)(rowBase + row) * 256 + k0 + kc);
      f16x4 hv = { (_Float16)v.x, (_Float16)v.y, (_Float16)v.z, (_Float16)v.w };
      *(f16x4*)&Al[row * 36 + kc] = hv;
    }
#pragma unroll
    for (int i = 0; i < 8; ++i) {
      int idx = tid + 256 * i;
      int k = idx >> 6, n = idx & 63;
      Bl[n * 36 + k] = (_Float16)W1[(size_t)(k0 + k) * GG + colBase + n];
    }
    __syncthreads();

#pragma unroll
    for (int kk = 0; kk < 2; ++kk) {
      int ka = (lane >> 4) * 4 + kk * 16;
      f16x4 af[4], bf[2];
#pragma unroll
      for (int mi = 0; mi < 4; ++mi)
        af[mi] = *(const f16x4*)&Al[(wr * 64 + mi * 16 + (lane & 15)) * 36 + ka];
#pragma unroll
      for (int ni = 0; ni < 2; ++ni)
        bf[ni] = *(const f16x4*)&Bl[(wc * 32 + ni * 16 + (lane & 15)) * 36 + ka];
#pragma unroll
      for (int mi = 0; mi < 4; ++mi)
#pragma unroll
        for (int ni = 0; ni < 2; ++ni)
          acc[mi][ni] = __builtin_amdgcn_mfma_f32_16x16x16f16(af[mi], bf[ni], acc[mi][ni], 0, 0, 0);
    }
    __syncthreads();
  }

#pragma unroll
  for (int ni = 0; ni < 2; ++ni) {
    int col = colBase + wc * 32 + ni * 16 + (lane & 15);
    float bias = b1[col] + b2[col];
#pragma unroll
    for (int mi = 0; mi < 4; ++mi) {
      int r0 = rowBase + wr * 64 + mi * 16 + (lane >> 4) * 4;
#pragma unroll
      for (int rr = 0; rr < 4; ++rr)
        pre[(size_t)(r0 + rr) * GG + col] = (_Float16)(acc[mi][ni][rr] + bias);
    }
  }
}

// ---------------- kernel 2: the recurrence ----------------
// 32 blocks, 256 threads (4 waves, 1/SIMD -> 244 arch + 256 acc regs). Thread t
// owns all 4 gate columns of es-index t. Same storage split as round 8 (proven
// resident); this round software-pipelines the step to kill exposed latency:
//  - LDS chunk 0 issued BEFORE part A; rolling depth-1 staging thereafter
//  - AGPR section interleaved with LDS chunk consume/issue
//  - readlanes hoisted in batches of 4 ahead of each 16-dot2 group
__global__ __launch_bounds__(256, 1)
__attribute__((amdgpu_waves_per_eu(1, 1)))
void k_lstm_rec(
    const _Float16* __restrict__ pre, const u32* __restrict__ W2p,
    const float* __restrict__ h0, const float* __restrict__ c0,
    float* __restrict__ out1, float* __restrict__ out2,
    float* __restrict__ hN, float* __restrict__ cN) {
  extern __shared__ __attribute__((aligned(16))) char smem[];
  uint4* W2Lw = (uint4*)smem;                               // NLC*1024 uint4 = 65536 B
  const uint4* W2L = (const uint4*)smem;
  _Float16* hbuf = (_Float16*)(smem + NLC * 1024 * 16);     // [2][256] f16 = 1024 B

  const int t = threadIdx.x;   // es index 0..255
  const int b = blockIdx.x;
  const int lane = t & 63;

  // ---- arch-VGPR weights: h2-rows 0..MRV-1, cols {t, t+256, t+512, t+768} ----
  u32 wv0[MRV], wv1[MRV], wv2[MRV], wv3[MRV];
#pragma unroll
  for (int m = 0; m < MRV; ++m) {
    wv0[m] = W2p[m * GG + t];
    wv1[m] = W2p[m * GG + t + 256];
    wv2[m] = W2p[m * GG + t + 512];
    wv3[m] = W2p[m * GG + t + 768];
  }
#pragma unroll
  for (int m = 0; m < MRV; ++m)
    asm volatile("" : "+v"(wv0[m]), "+v"(wv1[m]), "+v"(wv2[m]), "+v"(wv3[m]));  // pin ONCE

  // ---- AGPR weights: h2-rows MRV..MRV+MRA-1, explicit accvgpr_write ----
  u32 wa0[MRA], wa1[MRA], wa2[MRA], wa3[MRA];
#pragma unroll
  for (int m = 0; m < MRA; ++m) {
    u32 t0 = W2p[(MRV + m) * GG + t];
    u32 t1 = W2p[(MRV + m) * GG + t + 256];
    u32 t2 = W2p[(MRV + m) * GG + t + 512];
    u32 t3 = W2p[(MRV + m) * GG + t + 768];
    asm("v_accvgpr_write_b32 %0, %1" : "=a"(wa0[m]) : "v"(t0));
    asm("v_accvgpr_write_b32 %0, %1" : "=a"(wa1[m]) : "v"(t1));
    asm("v_accvgpr_write_b32 %0, %1" : "=a"(wa2[m]) : "v"(t2));
    asm("v_accvgpr_write_b32 %0, %1" : "=a"(wa3[m]) : "v"(t3));
  }

  // ---- LDS weights: h2-rows MRV+MRA..127, chunk c = rows MRV+MRA+4c..+3 ----
#pragma unroll
  for (int c = 0; c < NLC; ++c) {
    int m0 = MRV + MRA + 4 * c;
#pragma unroll
    for (int g = 0; g < 4; ++g) {
      uint4 v;
      v.x = W2p[(m0 + 0) * GG + t + 256 * g];
      v.y = W2p[(m0 + 1) * GG + t + 256 * g];
      v.z = W2p[(m0 + 2) * GG + t + 256 * g];
      v.w = W2p[(m0 + 3) * GG + t + 256 * g];
      W2Lw[c * 1024 + t + 256 * g] = v;
    }
  }

  float creg = c0[b * ESZ + t];
  hbuf[t] = (_Float16)h0[b * ESZ + t];
  float hlast = 0.f;
  __syncthreads();

  const _Float16* preB = pre + (size_t)b * TT * GG;
  _Float16 q0 = preB[t], q1 = preB[t + 256], q2 = preB[t + 512], q3 = preB[t + 768];

  for (int s = 0; s < TT; ++s) {
    const u32* hrow = (const u32*)(hbuf + (s & 1) * 256);  // h as 128 h2
    u32 hv0 = hrow[lane];        // h2-rows 0..63 spread over lanes
    u32 hv1 = hrow[64 + lane];   // h2-rows 64..127

    // issue LDS chunk 0 NOW: ~480 VALU cycles of part A cover its latency
    uint4 st0 = W2L[t], st1 = W2L[t + 256], st2 = W2L[t + 512], st3 = W2L[t + 768];

    float A0 = (float)q0, A1 = (float)q1, A2 = (float)q2, A3 = (float)q3;
    if (s + 1 < TT) {  // prefetch next step's pre (stays in flight across barrier)
      const _Float16* pn = preB + (size_t)(s + 1) * GG;
      q0 = pn[t]; q1 = pn[t + 256]; q2 = pn[t + 512]; q3 = pn[t + 768];
    }

    // ---- part A: arch rows 0..47, readlanes batched by 4 ----
#pragma unroll
    for (int g = 0; g < MRV / 4; ++g) {
      u32 s0 = (u32)__builtin_amdgcn_readlane((int)hv0, 4 * g + 0);
      u32 s1 = (u32)__builtin_amdgcn_readlane((int)hv0, 4 * g + 1);
      u32 s2 = (u32)__builtin_amdgcn_readlane((int)hv0, 4 * g + 2);
      u32 s3 = (u32)__builtin_amdgcn_readlane((int)hv0, 4 * g + 3);
      A0 = fdot2u(s0, wv0[4 * g + 0], A0);
      A1 = fdot2u(s0, wv1[4 * g + 0], A1);
      A2 = fdot2u(s0, wv2[4 * g + 0], A2);
      A3 = fdot2u(s0, wv3[4 * g + 0], A3);
      A0 = fdot2u(s1, wv0[4 * g + 1], A0);
      A1 = fdot2u(s1, wv1[4 * g + 1], A1);
      A2 = fdot2u(s1, wv2[4 * g + 1], A2);
      A3 = fdot2u(s1, wv3[4 * g + 1], A3);
      A0 = fdot2u(s2, wv0[4 * g + 2], A0);
      A1 = fdot2u(s2, wv1[4 * g + 2], A1);
      A2 = fdot2u(s2, wv2[4 * g + 2], A2);
      A3 = fdot2u(s2, wv3[4 * g + 2], A3);
      A0 = fdot2u(s3, wv0[4 * g + 3], A0);
      A1 = fdot2u(s3, wv1[4 * g + 3], A1);
      A2 = fdot2u(s3, wv2[4 * g + 3], A2);
      A3 = fdot2u(s3, wv3[4 * g + 3], A3);
    }

    // ---- parts B+C interleaved: 4 blocks of {4 AGPR groups, then LDS chunk} ----
#pragma unroll
    for (int blk = 0; blk < 4; ++blk) {
      // 4 AGPR groups: rows 48+16*blk .. 63+16*blk
#pragma unroll
      for (int gi = 0; gi < 4; ++gi) {
        const int i0 = 16 * blk + 4 * gi;      // AGPR array index; row = MRV+i0
        const int row = MRV + i0;
        u32 s0 = (row + 0 < 64) ? (u32)__builtin_amdgcn_readlane((int)hv0, row + 0)
                                : (u32)__builtin_amdgcn_readlane((int)hv1, row - 64);
        u32 s1 = (row + 1 < 64) ? (u32)__builtin_amdgcn_readlane((int)hv0, row + 1)
                                : (u32)__builtin_amdgcn_readlane((int)hv1, row - 63);
        u32 s2 = (row + 2 < 64) ? (u32)__builtin_amdgcn_readlane((int)hv0, row + 2)
                                : (u32)__builtin_amdgcn_readlane((int)hv1, row - 62);
        u32 s3 = (row + 3 < 64) ? (u32)__builtin_amdgcn_readlane((int)hv0, row + 3)
                                : (u32)__builtin_amdgcn_readlane((int)hv1, row - 61);
        u32 hx[4] = {s0, s1, s2, s3};
#pragma unroll
        for (int r = 0; r < 4; ++r) {
          u32 t0, t1, t2, t3;
          asm("v_accvgpr_read_b32 %0, %1" : "=v"(t0) : "a"(wa0[i0 + r]));
          asm("v_accvgpr_read_b32 %0, %1" : "=v"(t1) : "a"(wa1[i0 + r]));
          asm("v_accvgpr_read_b32 %0, %1" : "=v"(t2) : "a"(wa2[i0 + r]));
          asm("v_accvgpr_read_b32 %0, %1" : "=v"(t3) : "a"(wa3[i0 + r]));
          A0 = fdot2u(hx[r], t0, A0);
          A1 = fdot2u(hx[r], t1, A1);
          A2 = fdot2u(hx[r], t2, A2);
          A3 = fdot2u(hx[r], t3, A3);
        }
      }
      // consume LDS chunk blk (rows 112+4*blk..115+4*blk -> hv1 lanes 48+4*blk..)
      {
        const int lbase = (MRV + MRA - 64) + 4 * blk;   // 48 + 4*blk
        u32 s0 = (u32)__builtin_amdgcn_readlane((int)hv1, lbase + 0);
        u32 s1 = (u32)__builtin_amdgcn_readlane((int)hv1, lbase + 1);
        u32 s2 = (u32)__builtin_amdgcn_readlane((int)hv1, lbase + 2);
        u32 s3 = (u32)__builtin_amdgcn_readlane((int)hv1, lbase + 3);
        u32 c0x[4] = {st0.x, st0.y, st0.z, st0.w};
        u32 c1x[4] = {st1.x, st1.y, st1.z, st1.w};
        u32 c2x[4] = {st2.x, st2.y, st2.z, st2.w};
        u32 c3x[4] = {st3.x, st3.y, st3.z, st3.w};
        u32 hx[4] = {s0, s1, s2, s3};
#pragma unroll
        for (int r = 0; r < 4; ++r) {
          A0 = fdot2u(hx[r], c0x[r], A0);
          A1 = fdot2u(hx[r], c1x[r], A1);
          A2 = fdot2u(hx[r], c2x[r], A2);
          A3 = fdot2u(hx[r], c3x[r], A3);
        }
        if (blk < 3) {  // issue chunk blk+1 (consumed one block = ~380 cyc later)
          st0 = W2L[(blk + 1) * 1024 + t];
          st1 = W2L[(blk + 1) * 1024 + t + 256];
          st2 = W2L[(blk + 1) * 1024 + t + 512];
          st3 = W2L[(blk + 1) * 1024 + t + 768];
        }
      }
    }

    // gates all thread-local: f=A0, i=A1, o=A2, ch=A3
    float fg = sigm_f(A0);
    float ig = sigm_f(A1);
    float og = sigm_f(A2);
    float ch = tanh_f(A3);
    creg = fg * creg + ig * ch;
    float hv = og * tanh_f(creg);
    hlast = hv;

    out1[(size_t)b * TT * ESZ + (size_t)s * ESZ + t] = hv;   // [B, T*es]
    out2[(size_t)s * (BB * ESZ) + b * ESZ + t] = hv;         // [T, B, es]
    hbuf[((s & 1) ^ 1) * 256 + t] = (_Float16)hv;            // next step's h

    // one barrier/step; LDS-only drain (global loads/stores stay in flight)
    asm volatile("s_waitcnt lgkmcnt(0)" ::: "memory");
    __builtin_amdgcn_s_barrier();
  }

  hN[b * ESZ + t] = hlast;
  cN[b * ESZ + t] = creg;
}

// ---------------- launch ----------------
extern "C" void kernel_launch(void* const* d_in, const int* in_sizes, int n_in,
                              void* d_out, int out_size, void* d_ws, size_t ws_size,
                              hipStream_t stream) {
  const float* x  = (const float*)d_in[0];
  const float* h0 = (const float*)d_in[1];
  const float* c0 = (const float*)d_in[2];
  const float* W1 = (const float*)d_in[3];
  const float* W2 = (const float*)d_in[4];
  const float* b1 = (const float*)d_in[5];
  const float* b2 = (const float*)d_in[6];

  float* out1 = (float*)d_out;
  float* out2 = out1 + (size_t)BB * TT * ESZ;
  float* hN   = out2 + (size_t)BB * TT * ESZ;
  float* cN   = hN + BB * ESZ;

  _Float16* pre = (_Float16*)d_ws;                                  // 128 MB
  u32* W2p = (u32*)((char*)d_ws + (size_t)BB * TT * GG * 2);        // 512 KB

  k_pack_w2<<<512, 256, 0, stream>>>(W2, W2p);
  k_pre_gemm<<<dim3(512, 16), 256, 0, stream>>>(x, W1, b1, b2, pre);

  const int ldsBytes = NLC * 1024 * 16 + 1024;  // 65536 W2 + 2x256 f16 h buffers
  hipFuncSetAttribute((const void*)k_lstm_rec, hipFuncAttributeMaxDynamicSharedMemorySize, ldsBytes);
  k_lstm_rec<<<BB, 256, ldsBytes, stream>>>(pre, W2p, h0, c0, out1, out2, hN, cN);
}

// Round 10
// 3516.976 us; speedup vs baseline: 6.2394x; 1.1119x over previous
//
#include <hip/hip_runtime.h>

typedef unsigned int u32;
typedef unsigned short u16;
typedef unsigned long long u64;
typedef __attribute__((ext_vector_type(2))) _Float16 h2v;
typedef __attribute__((ext_vector_type(4))) _Float16 f16x4;
typedef __attribute__((ext_vector_type(4))) float f32x4;

#define BB 32
#define TT 2048
#define CC 256
#define ESZ 256
#define GG 1024   // 4*es
#define NG 4      // sibling blocks per batch
#define NW 128    // h2 words per batch (256 f16 = 128 pairs)

// ---------------- helpers ----------------
__device__ __forceinline__ float fdot2u(u32 a, u32 b, float c) {
#if __has_builtin(__builtin_amdgcn_fdot2)
  return __builtin_amdgcn_fdot2(__builtin_bit_cast(h2v, a), __builtin_bit_cast(h2v, b), c, false);
#else
  h2v av = __builtin_bit_cast(h2v, a), bv = __builtin_bit_cast(h2v, b);
  return c + (float)av[0] * (float)bv[0] + (float)av[1] * (float)bv[1];
#endif
}

__device__ __forceinline__ float sigm_f(float x) {
  float e = __builtin_amdgcn_exp2f(x * -1.442695041f);
  return __builtin_amdgcn_rcpf(1.0f + e);
}
__device__ __forceinline__ float tanh_f(float x) {
  float e = __builtin_amdgcn_exp2f(x * 2.885390082f);  // exp(2x)
  return 1.0f - 2.0f * __builtin_amdgcn_rcpf(e + 1.0f);
}

// ---------------- kernel 0a: pack W2 (f32 [256][1024] -> h2 rows [128][1024]) ----------------
__global__ void k_pack_w2(const float* __restrict__ W2, u32* __restrict__ W2p) {
  int gid = blockIdx.x * 256 + threadIdx.x;   // m = gid>>10, j = gid&1023
  int m = gid >> 10, j = gid & 1023;
  _Float16 lo = (_Float16)W2[(size_t)(2 * m) * GG + j];
  _Float16 hi = (_Float16)W2[(size_t)(2 * m + 1) * GG + j];
  W2p[gid] = (u32)__builtin_bit_cast(u16, lo) | ((u32)__builtin_bit_cast(u16, hi) << 16);
}

// ---------------- kernel 0b: init exchange slab (slot0 = tag0 + h0; slot1 = 0) ----------------
__global__ void k_init_slab(const float* __restrict__ h0, u64* __restrict__ slab) {
  int idx = blockIdx.x * 256 + threadIdx.x;   // 0..8191
  int slot = idx >> 12;                       // 4096 words per slot
  int rem = idx & 4095;
  int b = rem >> 7, r = rem & 127;
  u64 word = 0;
  if (slot == 0) {
    _Float16 lo = (_Float16)h0[b * ESZ + 2 * r];
    _Float16 hi = (_Float16)h0[b * ESZ + 2 * r + 1];
    u32 h2 = (u32)__builtin_bit_cast(u16, lo) | ((u32)__builtin_bit_cast(u16, hi) << 16);
    word = ((u64)h2 << 32);                   // tag = 0
  }
  slab[(size_t)slot * (BB * NW) + b * NW + r] = word;
}

// ---------------- kernel 1: pre = x@W1 + b1 + b2  (f16 MFMA, out f16 [B*T][1024]) ----------------
__global__ __launch_bounds__(256, 2) void k_pre_gemm(
    const float* __restrict__ x, const float* __restrict__ W1,
    const float* __restrict__ b1, const float* __restrict__ b2,
    _Float16* __restrict__ pre) {
  __shared__ __attribute__((aligned(16))) _Float16 Al[128 * 36];
  __shared__ __attribute__((aligned(16))) _Float16 Bl[64 * 36];
  const int tid = threadIdx.x;
  const int lane = tid & 63, wv = tid >> 6;
  const int wr = wv >> 1, wc = wv & 1;
  const int rowBase = blockIdx.x * 128;
  const int colBase = blockIdx.y * 64;

  f32x4 acc[4][2];
#pragma unroll
  for (int mi = 0; mi < 4; ++mi)
#pragma unroll
    for (int ni = 0; ni < 2; ++ni) acc[mi][ni] = (f32x4){0.f, 0.f, 0.f, 0.f};

  for (int k0 = 0; k0 < 256; k0 += 32) {
#pragma unroll
    for (int i = 0; i < 4; ++i) {
      int fidx = tid + 256 * i;
      int row = fidx >> 3, kc = (fidx & 7) * 4;
      const float4 v = *(const float4*)(x + (size_t)(rowBase + row) * 256 + k0 + kc);
      f16x4 hv = { (_Float16)v.x, (_Float16)v.y, (_Float16)v.z, (_Float16)v.w };
      *(f16x4*)&Al[row * 36 + kc] = hv;
    }
#pragma unroll
    for (int i = 0; i < 8; ++i) {
      int idx = tid + 256 * i;
      int k = idx >> 6, n = idx & 63;
      Bl[n * 36 + k] = (_Float16)W1[(size_t)(k0 + k) * GG + colBase + n];
    }
    __syncthreads();

#pragma unroll
    for (int kk = 0; kk < 2; ++kk) {
      int ka = (lane >> 4) * 4 + kk * 16;
      f16x4 af[4], bf[2];
#pragma unroll
      for (int mi = 0; mi < 4; ++mi)
        af[mi] = *(const f16x4*)&Al[(wr * 64 + mi * 16 + (lane & 15)) * 36 + ka];
#pragma unroll
      for (int ni = 0; ni < 2; ++ni)
        bf[ni] = *(const f16x4*)&Bl[(wc * 32 + ni * 16 + (lane & 15)) * 36 + ka];
#pragma unroll
      for (int mi = 0; mi < 4; ++mi)
#pragma unroll
        for (int ni = 0; ni < 2; ++ni)
          acc[mi][ni] = __builtin_amdgcn_mfma_f32_16x16x16f16(af[mi], bf[ni], acc[mi][ni], 0, 0, 0);
    }
    __syncthreads();
  }

#pragma unroll
  for (int ni = 0; ni < 2; ++ni) {
    int col = colBase + wc * 32 + ni * 16 + (lane & 15);
    float bias = b1[col] + b2[col];
#pragma unroll
    for (int mi = 0; mi < 4; ++mi) {
      int r0 = rowBase + wr * 64 + mi * 16 + (lane >> 4) * 4;
#pragma unroll
      for (int rr = 0; rr < 4; ++rr)
        pre[(size_t)(r0 + rr) * GG + col] = (_Float16)(acc[mi][ni][rr] + bias);
    }
  }
}

// ---------------- kernel 2: the recurrence, 4 CUs per batch ----------------
// Grid 128 = NG*32; bid = g*32 + b (siblings of batch b congruent mod 8 ->
// likely same XCD; correctness placement-independent via agent-scope atomics).
// Block g handles es indices [64g, 64g+64): 256 threads, 1 gate-column each.
// Wave w covers es [64g+16w, +16) x 4 gates -> gate combine via __shfl only.
// Weights: 128 h2-rows per column, ALL in arch VGPRs. No LDS, no barriers.
// h exchange: tagged u64 words {h2pair<<32 | (s+1)} in a parity-double-buffered
// LLC slab; readers spin on exactly their 2 words (tag==s). Double-buffering
// orders overwrites behind all readers (full wave-to-wave dependency).
__global__ __launch_bounds__(256, 1)
__attribute__((amdgpu_waves_per_eu(1, 1)))
void k_lstm_rec(
    const _Float16* __restrict__ pre, const u32* __restrict__ W2p,
    const float* __restrict__ c0, u64* __restrict__ slab,
    float* __restrict__ out1, float* __restrict__ out2,
    float* __restrict__ hN, float* __restrict__ cN) {
  const int bid = blockIdx.x;
  const int b = bid & 31;        // batch
  const int g = bid >> 5;        // sibling 0..3
  const int t = threadIdx.x;
  const int l = t & 63;          // lane
  const int w = t >> 6;          // wave 0..3
  const int es_l = l & 15;       // es slot within wave
  const int gate = l >> 4;       // 0:f 1:i 2:o 3:ch
  const int E0 = 64 * g + 16 * w;
  const int j = E0 + es_l;               // es index this lane combines
  const int col = j + 256 * gate;        // gate column this lane dots

  // all 128 weight h2-rows for this column in arch VGPRs
  u32 wreg[128];
#pragma unroll
  for (int m = 0; m < 128; ++m) wreg[m] = W2p[m * GG + col];

  float creg = c0[b * ESZ + j];  // replicated across the 4 gate-lanes of j

  const _Float16* preB = pre + (size_t)b * TT * GG;
  _Float16 q = preB[col];

  const int rA = l;              // this thread's two h2 rows
  const int rB = 64 + l;
  float hv_keep = 0.f;

  for (int s = 0; s < TT; ++s) {
    // ---- poll input h (tag == s) from slot s&1; detection IS the data load ----
    u64* basep = slab + (size_t)(s & 1) * (BB * NW) + b * NW;
    u64 wA, wB;
    u32 want = (u32)s;
    do {
      wA = __hip_atomic_load(&basep[rA], __ATOMIC_RELAXED, __HIP_MEMORY_SCOPE_AGENT);
    } while ((u32)wA != want);
    do {
      wB = __hip_atomic_load(&basep[rB], __ATOMIC_RELAXED, __HIP_MEMORY_SCOPE_AGENT);
    } while ((u32)wB != want);
    u32 hvA = (u32)(wA >> 32);   // h2 row l
    u32 hvB = (u32)(wB >> 32);   // h2 row 64+l

    float A0 = 0.f, A1 = 0.f, A2 = 0.f, A3 = 0.f;
    float qf = (float)q;
    if (s + 1 < TT) q = preB[(size_t)(s + 1) * GG + col];  // prefetch next pre

    // 128-row dot, 4 independent chains, h distributed via readlane
#pragma unroll
    for (int m = 0; m < 32; ++m) {
      u32 h0m = (u32)__builtin_amdgcn_readlane((int)hvA, m);
      u32 h1m = (u32)__builtin_amdgcn_readlane((int)hvA, 32 + m);
      u32 h2m = (u32)__builtin_amdgcn_readlane((int)hvB, m);
      u32 h3m = (u32)__builtin_amdgcn_readlane((int)hvB, 32 + m);
      A0 = fdot2u(h0m, wreg[m], A0);
      A1 = fdot2u(h1m, wreg[32 + m], A1);
      A2 = fdot2u(h2m, wreg[64 + m], A2);
      A3 = fdot2u(h3m, wreg[96 + m], A3);
    }
    float v = qf + ((A0 + A1) + (A2 + A3));
    float gv = (gate == 3) ? tanh_f(v) : sigm_f(v);

    // gate combine within wave (no LDS, no barrier)
    float fg = __shfl(gv, es_l);
    float ig = __shfl(gv, es_l + 16);
    float og = __shfl(gv, es_l + 32);
    float ch = __shfl(gv, es_l + 48);
    creg = fg * creg + ig * ch;                 // consistent across the 4 lanes of j
    float hv = og * tanh_f(creg);
    hv_keep = hv;

    if (l < 16) {
      out1[(size_t)b * TT * ESZ + (size_t)s * ESZ + j] = hv;   // [B, T*es]
      out2[(size_t)s * (BB * ESZ) + b * ESZ + j] = hv;         // [T, B, es]
    }

    // publish: even es-lanes of the gate-0 group write tagged h2-pair words
    float hp = __shfl_xor(hv, 1);               // partner es value
    if (l < 16 && (es_l & 1) == 0) {
      _Float16 lo16 = (_Float16)hv, hi16 = (_Float16)hp;
      u32 h2p = (u32)__builtin_bit_cast(u16, lo16) | ((u32)__builtin_bit_cast(u16, hi16) << 16);
      u64 word = ((u64)h2p << 32) | (u32)(s + 1);
      int r = (E0 + es_l) >> 1;                 // h2 row index
      u64* outp = slab + (size_t)((s + 1) & 1) * (BB * NW) + b * NW + r;
      __hip_atomic_store(outp, word, __ATOMIC_RELAXED, __HIP_MEMORY_SCOPE_AGENT);
    }
  }

  if (l < 16) {
    hN[b * ESZ + j] = hv_keep;
    cN[b * ESZ + j] = creg;
  }
}

// ---------------- launch ----------------
extern "C" void kernel_launch(void* const* d_in, const int* in_sizes, int n_in,
                              void* d_out, int out_size, void* d_ws, size_t ws_size,
                              hipStream_t stream) {
  const float* x  = (const float*)d_in[0];
  const float* h0 = (const float*)d_in[1];
  const float* c0 = (const float*)d_in[2];
  const float* W1 = (const float*)d_in[3];
  const float* W2 = (const float*)d_in[4];
  const float* b1 = (const float*)d_in[5];
  const float* b2 = (const float*)d_in[6];

  float* out1 = (float*)d_out;
  float* out2 = out1 + (size_t)BB * TT * ESZ;
  float* hN   = out2 + (size_t)BB * TT * ESZ;
  float* cN   = hN + BB * ESZ;

  _Float16* pre = (_Float16*)d_ws;                                  // 128 MB
  u32* W2p = (u32*)((char*)d_ws + (size_t)BB * TT * GG * 2);        // 512 KB
  u64* slab = (u64*)((char*)W2p + 128 * GG * 4);                    // 64 KB

  k_pack_w2<<<512, 256, 0, stream>>>(W2, W2p);
  k_init_slab<<<32, 256, 0, stream>>>(h0, slab);
  k_pre_gemm<<<dim3(512, 16), 256, 0, stream>>>(x, W1, b1, b2, pre);

  k_lstm_rec<<<NG * BB, 256, 0, stream>>>(pre, W2p, c0, slab, out1, out2, hN, cN);
}